// Round 7
// baseline (1031.233 us; speedup 1.0000x reference)
//
#include <hip/hip_runtime.h>

#define N_EDGE 262144
#define N_TRI  1048576
#define DIM    128
#define NRBF   6
#define ADIM   49
#define NBIL   8
#define TE     64
#define NTHR   256
#define SXD    68    // activation LDS row stride in dwords (272 B)
#define EB2    2048  // edges per seg_reduce block
#define NSL    4     // kj slices

typedef __attribute__((ext_vector_type(8))) short bf16x8;
typedef __attribute__((ext_vector_type(4))) float f32x4;

__device__ __forceinline__ float silu_f(float x) { return x / (1.f + __expf(-x)); }
__device__ __forceinline__ unsigned short f2bf(float f) {
    unsigned int u = __float_as_uint(f);
    return (unsigned short)((u + 0x7FFFu + ((u >> 16) & 1u)) >> 16);
}
__device__ __forceinline__ unsigned int pk2(float x, float y) {
    unsigned int r;
    asm("v_cvt_pk_bf16_f32 %0, %1, %2" : "=v"(r) : "v"(x), "v"(y));
    return r;
}
__device__ __forceinline__ float bf2f(unsigned short u) {
    return __uint_as_float(((unsigned int)u) << 16);
}

// ---------------------------------------------------------------------------
// prep: weights -> bf16 [n][k_stored], k-permuted to match packed activations.
// k_stored = 32q + 2m + p  <->  k_orig = 32q + 16p + m
// slots: 0=nbr_m_w 1=m_ji_w 2=post_w 3..8=res_w(6), then fwb [n][j][l_stored]
// ---------------------------------------------------------------------------
__global__ __launch_bounds__(256) void prep_w_k(
    const float* __restrict__ nbr, const float* __restrict__ mji,
    const float* __restrict__ post, const float* __restrict__ res,
    const float* __restrict__ fw, unsigned short* __restrict__ wt)
{
    int idx = blockIdx.x * 256 + threadIdx.x;          // 278528 total
    if (idx < 9 * 16384) {
        int m = idx >> 14, rr = idx & 16383;
        int n = rr >> 7, ks = rr & 127;
        int ko = (ks & ~31) | ((ks & 1) << 4) | ((ks >> 1) & 15);
        const float* src = (m == 0) ? nbr : (m == 1) ? mji : (m == 2) ? post
                          : (res + (size_t)(m - 3) * 16384);
        wt[idx] = f2bf(src[ko * DIM + n]);
    } else {
        int r2 = idx - 9 * 16384;                      // n*1024 + j*128 + ls
        int n = r2 >> 10, j = (r2 >> 7) & 7, ls = r2 & 127;
        int lo = (ls & ~31) | ((ls & 1) << 4) | ((ls >> 1) & 15);
        wt[idx] = f2bf(fw[(size_t)(n * NBIL + j) * DIM + lo]);
    }
}

// ---------------------------------------------------------------------------
// triplet stage A: ta[w][8] = a_sbf[w] @ a_sbf_w  (coalesced write)
// ---------------------------------------------------------------------------
__global__ __launch_bounds__(256) void ta_all_k(
    const float* __restrict__ a_sbf, const float* __restrict__ a_sbf_w,
    float* __restrict__ taw)
{
    __shared__ __align__(16) float sA[256 * ADIM];
    __shared__ float sWa[ADIM * NBIL];
    const int tid = threadIdx.x;
    const size_t w0 = (size_t)blockIdx.x * 256;

    {
        const float4* src = (const float4*)(a_sbf + w0 * ADIM);
        float4* dst = (float4*)sA;
        for (int i = tid; i < (256 * ADIM) / 4; i += 256) dst[i] = src[i];
    }
    for (int i = tid; i < ADIM * NBIL; i += 256) sWa[i] = a_sbf_w[i];
    __syncthreads();

    float ta[NBIL];
    #pragma unroll
    for (int j = 0; j < NBIL; ++j) ta[j] = 0.0f;
    const float* row = sA + tid * ADIM;
    #pragma unroll
    for (int k = 0; k < ADIM; ++k) {
        float v = row[k];
        #pragma unroll
        for (int j = 0; j < NBIL; ++j) ta[j] = fmaf(v, sWa[k * NBIL + j], ta[j]);
    }
    float4* dst = (float4*)(taw + (w0 + tid) * NBIL);
    dst[0] = make_float4(ta[0], ta[1], ta[2], ta[3]);
    dst[1] = make_float4(ta[4], ta[5], ta[6], ta[7]);
}

// ---------------------------------------------------------------------------
// triplet stage B: grid = 128 edge-groups x 4 kj-slices. LDS bin per group,
// coalesced atomic writeback.
// ---------------------------------------------------------------------------
__global__ __launch_bounds__(1024) void seg_reduce_k(
    const float* __restrict__ taw, const int* __restrict__ kj_idx,
    float* __restrict__ ta_sum)
{
    __shared__ float acc[EB2 * NBIL];                  // 64 KB
    const int tid = threadIdx.x;
    const int eg = blockIdx.x >> 2;
    const int sl = blockIdx.x & 3;
    const int lo = eg * EB2;

    for (int i = tid; i < EB2 * NBIL; i += 1024) acc[i] = 0.f;
    __syncthreads();

    const int4* kj4 = (const int4*)kj_idx;
    const int i0 = sl * (N_TRI / 4 / NSL);
    const int i1 = i0 + (N_TRI / 4 / NSL);
    for (int i = i0 + tid; i < i1; i += 1024) {
        int4 v = kj4[i];
        int w0 = i * 4;
        #pragma unroll
        for (int k = 0; k < 4; ++k) {
            int e = (k == 0) ? v.x : (k == 1) ? v.y : (k == 2) ? v.z : v.w;
            unsigned d = (unsigned)(e - lo);
            if (d < (unsigned)EB2) {
                const float4* p = (const float4*)(taw + (size_t)(w0 + k) * NBIL);
                float4 a = p[0], b = p[1];
                float* q = acc + d * NBIL;
                atomicAdd(q + 0, a.x); atomicAdd(q + 1, a.y);
                atomicAdd(q + 2, a.z); atomicAdd(q + 3, a.w);
                atomicAdd(q + 4, b.x); atomicAdd(q + 5, b.y);
                atomicAdd(q + 6, b.z); atomicAdd(q + 7, b.w);
            }
        }
    }
    __syncthreads();
    for (int i = tid; i < EB2 * NBIL; i += 1024)
        unsafeAtomicAdd(ta_sum + (size_t)lo * NBIL + i, acc[i]);
}

// ---------------------------------------------------------------------------
// fused edge kernel: TE=64, 4 waves (col-split). Packed-dword k-permuted
// activations, zero-C MFMA seeding, transposed ta/e_rbf staging.
// ---------------------------------------------------------------------------
__global__ __launch_bounds__(NTHR) void edge_main_k(
    const float* __restrict__ m_ji, const float* __restrict__ e_rbf,
    const float* __restrict__ ta_sum, const unsigned short* __restrict__ wt,
    const float* __restrict__ nbr_m_b, const float* __restrict__ e_rbf_w,
    const float* __restrict__ m_ji_b, const float* __restrict__ post_b,
    const float* __restrict__ res_b, float* __restrict__ out)
{
    __shared__ __align__(16) unsigned int sXd[TE * SXD];   // 17.4 KB
    __shared__ __align__(16) float sTAT[NBIL * TE];        // ta transposed
    __shared__ __align__(16) float sET[NRBF * TE];         // e_rbf transposed
    __shared__ float sEw[NRBF * DIM];
    __shared__ float sBias[9 * DIM];

    const int tid  = threadIdx.x;
    const int lane = tid & 63;
    const int ml   = lane & 15;
    const int g    = lane >> 4;
    const int wq   = tid >> 6;         // wave id 0..3
    const int n0   = wq * 32;
    const int q16  = wq * 16;
    const size_t e0 = (size_t)blockIdx.x * TE;

    bf16x8 A[4][2], Bf[2][4];
    f32x4 acc[4][2], xr[4][2], zac;
    unsigned int trp[4][4];            // transf packed bf16 pairs

    auto prefB = [&](const unsigned short* wtm, int ldk, int kbase) {
        #pragma unroll
        for (int nt = 0; nt < 2; ++nt) {
            const unsigned short* wb =
                wtm + (size_t)(n0 + nt * 16 + ml) * ldk + kbase + g * 8;
            #pragma unroll
            for (int ks = 0; ks < 4; ++ks)
                Bf[nt][ks] = *(const bf16x8*)(wb + ks * 32);
        }
    };
    auto prefBh = [&](const unsigned short* wtm, int ldk, int kbase, int h) {
        #pragma unroll
        for (int nt = 0; nt < 2; ++nt) {
            const unsigned short* wb =
                wtm + (size_t)(n0 + nt * 16 + ml) * ldk + kbase + g * 8;
            #pragma unroll
            for (int kk = 0; kk < 2; ++kk)
                Bf[nt][h * 2 + kk] = *(const bf16x8*)(wb + (h * 2 + kk) * 32);
        }
    };

    prefB(wt + 1 * 16384, DIM, 0);                     // m_ji_w for stage 1
    zac[0] = 0.f; zac[1] = 0.f; zac[2] = 0.f; zac[3] = 0.f;

    // ---- prologue staging: m_ji packed+permuted, ta/e transposed, consts
    #pragma unroll
    for (int i = 0; i < 16; ++i) {
        int idx = tid + i * NTHR;                      // 4096 dwords
        int row = idx >> 6, d = idx & 63;
        int dq = d >> 4, c = d & 15;
        const float* src = m_ji + (e0 + row) * DIM + dq * 32 + c;
        sXd[row * SXD + d] = pk2(src[0], src[16]);
    }
    #pragma unroll
    for (int i = 0; i < 2; ++i) {
        int idx = tid + i * NTHR;                      // 512: j-major
        int j = idx >> 6, e = idx & 63;
        sTAT[j * TE + e] = ta_sum[(e0 + e) * NBIL + j];
    }
    for (int i = tid; i < NRBF * TE; i += NTHR) {      // FIXED: loop (384>256)
        int j = i >> 6, e = i & 63;
        sET[j * TE + e] = e_rbf[(e0 + e) * NRBF + j];
    }
    for (int i = tid; i < NRBF * DIM; i += NTHR) sEw[i] = e_rbf_w[i];
    for (int i = tid; i < 9 * DIM; i += NTHR) {
        int seg = i >> 7, off = i & 127;
        const float* p = (seg == 0) ? nbr_m_b : (seg == 1) ? m_ji_b
                       : (seg == 2) ? post_b : (res_b + (seg - 3) * DIM);
        sBias[i] = p[off];
    }
    __syncthreads();

    auto loadA = [&](int h) {
        const unsigned short* base = (const unsigned short*)sXd;
        #pragma unroll
        for (int mt = 0; mt < 4; ++mt) {
            const unsigned short* rb = base + (mt * 16 + ml) * (SXD * 2) + h * 64 + g * 8;
            A[mt][0] = *(const bf16x8*)(rb);
            A[mt][1] = *(const bf16x8*)(rb + 32);
        }
    };
    auto mfmaH = [&](int h) {
        #pragma unroll
        for (int nt = 0; nt < 2; ++nt)
        #pragma unroll
        for (int kk = 0; kk < 2; ++kk) {
            #pragma unroll
            for (int mt = 0; mt < 4; ++mt)
                acc[mt][nt] = __builtin_amdgcn_mfma_f32_16x16x32_bf16(
                    A[mt][kk], Bf[nt][h * 2 + kk], acc[mt][nt], 0, 0, 0);
        }
    };
    auto gemm_full = [&]() { loadA(0); mfmaH(0); loadA(1); mfmaH(1); };
    auto init_bias = [&](int slot) {
        #pragma unroll
        for (int nt = 0; nt < 2; ++nt) {
            float bv = sBias[slot * DIM + n0 + nt * 16 + ml];
            #pragma unroll
            for (int mt = 0; mt < 4; ++mt)
            #pragma unroll
            for (int r = 0; r < 4; ++r) acc[mt][nt][r] = bv;
        }
    };
    auto store_sX = [&](f32x4 (&v)[4][2]) {            // packed dwords, guarded
        __syncthreads();
        #pragma unroll
        for (int mt = 0; mt < 4; ++mt)
        #pragma unroll
        for (int r = 0; r < 4; ++r)
            sXd[(mt * 16 + g * 4 + r) * SXD + q16 + ml] = pk2(v[mt][0][r], v[mt][1][r]);
        __syncthreads();
    };

    // ---- S1: transf = silu(m_ji @ m_ji_w + b) -> packed regs
    init_bias(1);
    gemm_full();
    prefB(wt + 0 * 16384, DIM, 0);
    #pragma unroll
    for (int mt = 0; mt < 4; ++mt)
    #pragma unroll
    for (int r = 0; r < 4; ++r)
        trp[mt][r] = pk2(silu_f(acc[mt][0][r]), silu_f(acc[mt][1][r]));

    // ---- S2: me = silu(m_ji @ nbr_m_w + b) * (e_rbf @ e_rbf_w)  (A reused)
    init_bias(0);
    gemm_full();
    const unsigned short* fwb = wt + 9 * 16384;
    prefBh(fwb, NBIL * DIM, 0, 0);                     // bilinear (h0,j0)
    {
        float ewc[2][NRBF];
        #pragma unroll
        for (int nt = 0; nt < 2; ++nt)
        #pragma unroll
        for (int q = 0; q < NRBF; ++q) ewc[nt][q] = sEw[q * DIM + n0 + nt * 16 + ml];
        #pragma unroll
        for (int mt = 0; mt < 4; ++mt) {
            f32x4 er[NRBF];
            #pragma unroll
            for (int q = 0; q < NRBF; ++q)
                er[q] = *(const f32x4*)(sET + q * TE + mt * 16 + g * 4);
            #pragma unroll
            for (int r = 0; r < 4; ++r)
            #pragma unroll
            for (int nt = 0; nt < 2; ++nt) {
                float te = 0.f;
                #pragma unroll
                for (int q = 0; q < NRBF; ++q) te = fmaf(er[q][r], ewc[nt][q], te);
                acc[mt][nt][r] = silu_f(acc[mt][nt][r]) * te;
            }
        }
    }
    store_sX(acc);                                     // sXd = me

    // ---- S3 bilinear: xr = transf + sum_{h,j} ta_j * (me_h @ fw_{j,h}^T)
    #pragma unroll
    for (int mt = 0; mt < 4; ++mt)
    #pragma unroll
    for (int r = 0; r < 4; ++r) {
        unsigned int t = trp[mt][r];
        xr[mt][0][r] = bf2f((unsigned short)(t & 0xffff));
        xr[mt][1][r] = bf2f((unsigned short)(t >> 16));
    }
    #pragma unroll
    for (int h = 0; h < 2; ++h) {
        loadA(h);                                      // 8 reads, once per half
        for (int j = 0; j < NBIL; ++j) {
            #pragma unroll
            for (int kk = 0; kk < 2; ++kk)
            #pragma unroll
            for (int nt = 0; nt < 2; ++nt)
            #pragma unroll
            for (int mt = 0; mt < 4; ++mt)
                acc[mt][nt] = __builtin_amdgcn_mfma_f32_16x16x32_bf16(
                    A[mt][kk], Bf[nt][h * 2 + kk],
                    (kk == 0) ? zac : acc[mt][nt], 0, 0, 0);
            if (j < NBIL - 1)      prefBh(fwb, NBIL * DIM, (j + 1) * DIM, h);
            else if (h == 0)       prefBh(fwb, NBIL * DIM, 0, 1);
            else                   prefB(wt + 3 * 16384, DIM, 0);
            #pragma unroll
            for (int mt = 0; mt < 4; ++mt) {
                f32x4 tv = *(const f32x4*)(sTAT + j * TE + mt * 16 + g * 4);
                #pragma unroll
                for (int nt = 0; nt < 2; ++nt)
                #pragma unroll
                for (int r = 0; r < 4; ++r)
                    xr[mt][nt][r] = fmaf(tv[r], acc[mt][nt][r], xr[mt][nt][r]);
            }
        }
    }
    store_sX(xr);                                      // sXd = x

    // ---- res0
    init_bias(3); gemm_full(); prefB(wt + 4 * 16384, DIM, 0);
    #pragma unroll
    for (int mt = 0; mt < 4; ++mt)
    #pragma unroll
    for (int nt = 0; nt < 2; ++nt)
    #pragma unroll
    for (int r = 0; r < 4; ++r) acc[mt][nt][r] = silu_f(acc[mt][nt][r]);
    store_sX(acc);
    init_bias(4); gemm_full(); prefB(wt + 2 * 16384, DIM, 0);
    #pragma unroll
    for (int mt = 0; mt < 4; ++mt)
    #pragma unroll
    for (int nt = 0; nt < 2; ++nt)
    #pragma unroll
    for (int r = 0; r < 4; ++r) xr[mt][nt][r] += silu_f(acc[mt][nt][r]);
    store_sX(xr);

    // ---- post: x = silu(x @ post_w + b) + transf
    init_bias(2); gemm_full(); prefB(wt + 5 * 16384, DIM, 0);
    #pragma unroll
    for (int mt = 0; mt < 4; ++mt)
    #pragma unroll
    for (int r = 0; r < 4; ++r) {
        unsigned int t = trp[mt][r];
        xr[mt][0][r] = silu_f(acc[mt][0][r]) + bf2f((unsigned short)(t & 0xffff));
        xr[mt][1][r] = silu_f(acc[mt][1][r]) + bf2f((unsigned short)(t >> 16));
    }
    store_sX(xr);

    // ---- res1
    init_bias(5); gemm_full(); prefB(wt + 6 * 16384, DIM, 0);
    #pragma unroll
    for (int mt = 0; mt < 4; ++mt)
    #pragma unroll
    for (int nt = 0; nt < 2; ++nt)
    #pragma unroll
    for (int r = 0; r < 4; ++r) acc[mt][nt][r] = silu_f(acc[mt][nt][r]);
    store_sX(acc);
    init_bias(6); gemm_full(); prefB(wt + 7 * 16384, DIM, 0);
    #pragma unroll
    for (int mt = 0; mt < 4; ++mt)
    #pragma unroll
    for (int nt = 0; nt < 2; ++nt)
    #pragma unroll
    for (int r = 0; r < 4; ++r) xr[mt][nt][r] += silu_f(acc[mt][nt][r]);
    store_sX(xr);

    // ---- res2 + fused store
    init_bias(7); gemm_full(); prefB(wt + 8 * 16384, DIM, 0);
    #pragma unroll
    for (int mt = 0; mt < 4; ++mt)
    #pragma unroll
    for (int nt = 0; nt < 2; ++nt)
    #pragma unroll
    for (int r = 0; r < 4; ++r) acc[mt][nt][r] = silu_f(acc[mt][nt][r]);
    store_sX(acc);
    init_bias(8); gemm_full();
    #pragma unroll
    for (int mt = 0; mt < 4; ++mt)
    #pragma unroll
    for (int r = 0; r < 4; ++r) {
        int row = mt * 16 + g * 4 + r;
        out[(e0 + row) * DIM + n0 + ml]      = silu_f(acc[mt][0][r]) + xr[mt][0][r];
        out[(e0 + row) * DIM + n0 + 16 + ml] = silu_f(acc[mt][1][r]) + xr[mt][1][r];
    }
}

// ---------------------------------------------------------------------------
// fallback triplet (scattered hw atomics) when ws too small
// ---------------------------------------------------------------------------
__global__ __launch_bounds__(256) void triplet_atomic_k(
    const float* __restrict__ a_sbf, const float* __restrict__ a_sbf_w,
    const int* __restrict__ kj_idx, float* __restrict__ ta_sum)
{
    __shared__ __align__(16) float sA[256 * ADIM];
    __shared__ float sWa[ADIM * NBIL];
    const int tid = threadIdx.x;
    const size_t w0 = (size_t)blockIdx.x * 256;
    {
        const float4* src = (const float4*)(a_sbf + w0 * ADIM);
        float4* dst = (float4*)sA;
        for (int i = tid; i < (256 * ADIM) / 4; i += 256) dst[i] = src[i];
    }
    for (int i = tid; i < ADIM * NBIL; i += 256) sWa[i] = a_sbf_w[i];
    __syncthreads();
    float ta[NBIL];
    #pragma unroll
    for (int j = 0; j < NBIL; ++j) ta[j] = 0.0f;
    const float* row = sA + tid * ADIM;
    #pragma unroll
    for (int k = 0; k < ADIM; ++k) {
        float v = row[k];
        #pragma unroll
        for (int j = 0; j < NBIL; ++j) ta[j] = fmaf(v, sWa[k * NBIL + j], ta[j]);
    }
    const int e = kj_idx[w0 + tid];
    float* dst = ta_sum + (size_t)e * NBIL;
    #pragma unroll
    for (int j = 0; j < NBIL; ++j) unsafeAtomicAdd(dst + j, ta[j]);
}

// ---------------------------------------------------------------------------
extern "C" void kernel_launch(void* const* d_in, const int* in_sizes, int n_in,
                              void* d_out, int out_size, void* d_ws, size_t ws_size,
                              hipStream_t stream)
{
    (void)in_sizes; (void)n_in; (void)out_size;
    const float* m_ji    = (const float*)d_in[0];
    const float* e_rbf   = (const float*)d_in[1];
    const float* a_sbf   = (const float*)d_in[2];
    const int*   kj_idx  = (const int*)d_in[5];
    const float* nbr_m_w = (const float*)d_in[6];
    const float* nbr_m_b = (const float*)d_in[7];
    const float* e_rbf_w = (const float*)d_in[8];
    const float* a_sbf_w = (const float*)d_in[9];
    const float* final_w = (const float*)d_in[10];
    const float* m_ji_w  = (const float*)d_in[11];
    const float* m_ji_b  = (const float*)d_in[12];
    const float* post_w  = (const float*)d_in[13];
    const float* post_b  = (const float*)d_in[14];
    const float* res_w   = (const float*)d_in[15];
    const float* res_b   = (const float*)d_in[16];
    float* out = (float*)d_out;

    const size_t taB  = (size_t)N_EDGE * NBIL * sizeof(float);      // 8.4 MB
    const size_t wtB  = (size_t)278528 * sizeof(unsigned short);    // 0.56 MB
    const size_t tawB = (size_t)N_TRI * NBIL * sizeof(float);       // 33.6 MB

    float* ta_sum = (float*)d_ws;
    unsigned short* wt = (unsigned short*)((char*)d_ws + taB);
    float* taw = (float*)((char*)d_ws + taB + wtB);

    prep_w_k<<<1088, 256, 0, stream>>>(nbr_m_w, m_ji_w, post_w, res_w, final_w, wt);
    hipMemsetAsync(ta_sum, 0, taB, stream);

    if (ws_size >= taB + wtB + tawB) {
        ta_all_k<<<N_TRI / 256, 256, 0, stream>>>(a_sbf, a_sbf_w, taw);
        seg_reduce_k<<<(N_EDGE / EB2) * NSL, 1024, 0, stream>>>(taw, kj_idx, ta_sum);
    } else {
        triplet_atomic_k<<<N_TRI / 256, 256, 0, stream>>>(a_sbf, a_sbf_w, kj_idx, ta_sum);
    }
    edge_main_k<<<N_EDGE / TE, NTHR, 0, stream>>>(m_ji, e_rbf, ta_sum, wt,
        nbr_m_b, e_rbf_w, m_ji_b, post_b, res_b, out);
}

// Round 8
// 453.341 us; speedup vs baseline: 2.2747x; 2.2747x over previous
//
#include <hip/hip_runtime.h>

#define N_EDGE 262144
#define N_TRI  1048576
#define DIM    128
#define NRBF   6
#define ADIM   49
#define NBIL   8
#define TE     64
#define NTHR   256
#define SXD    68    // activation LDS row stride in dwords (272 B)
#define EB2    2048  // edges per seg_reduce block
#define NSL    4     // kj slices

typedef __attribute__((ext_vector_type(8))) short bf16x8;
typedef __attribute__((ext_vector_type(4))) float f32x4;

__device__ __forceinline__ float fast_rcp(float x) {
    float r; asm("v_rcp_f32 %0, %1" : "=v"(r) : "v"(x)); return r;
}
__device__ __forceinline__ float fast_exp2(float x) {
    float r; asm("v_exp_f32 %0, %1" : "=v"(r) : "v"(x)); return r;
}
__device__ __forceinline__ float silu_f(float x) {
    return x * fast_rcp(1.f + fast_exp2(-1.44269504f * x));
}
__device__ __forceinline__ unsigned short f2bf(float f) {
    unsigned int u = __float_as_uint(f);
    return (unsigned short)((u + 0x7FFFu + ((u >> 16) & 1u)) >> 16);
}
__device__ __forceinline__ unsigned int pk2(float x, float y) {
    unsigned int r;
    asm("v_cvt_pk_bf16_f32 %0, %1, %2" : "=v"(r) : "v"(x), "v"(y));
    return r;
}
__device__ __forceinline__ float bf2f(unsigned short u) {
    return __uint_as_float(((unsigned int)u) << 16);
}

// ---------------------------------------------------------------------------
// prep: weights -> bf16 [n][k_stored], k-permuted to match packed activations.
// k_stored = 32q + 2m + p  <->  k_orig = 32q + 16p + m
// slots: 0=nbr_m_w 1=m_ji_w 2=post_w 3..8=res_w(6), then fwb [n][j][l_stored]
// ---------------------------------------------------------------------------
__global__ __launch_bounds__(256) void prep_w_k(
    const float* __restrict__ nbr, const float* __restrict__ mji,
    const float* __restrict__ post, const float* __restrict__ res,
    const float* __restrict__ fw, unsigned short* __restrict__ wt)
{
    int idx = blockIdx.x * 256 + threadIdx.x;          // 278528 total
    if (idx < 9 * 16384) {
        int m = idx >> 14, rr = idx & 16383;
        int n = rr >> 7, ks = rr & 127;
        int ko = (ks & ~31) | ((ks & 1) << 4) | ((ks >> 1) & 15);
        const float* src = (m == 0) ? nbr : (m == 1) ? mji : (m == 2) ? post
                          : (res + (size_t)(m - 3) * 16384);
        wt[idx] = f2bf(src[ko * DIM + n]);
    } else {
        int r2 = idx - 9 * 16384;                      // n*1024 + j*128 + ls
        int n = r2 >> 10, j = (r2 >> 7) & 7, ls = r2 & 127;
        int lo = (ls & ~31) | ((ls & 1) << 4) | ((ls >> 1) & 15);
        wt[idx] = f2bf(fw[(size_t)(n * NBIL + j) * DIM + lo]);
    }
}

// ---------------------------------------------------------------------------
// triplet stage A: ta[w][8] = a_sbf[w] @ a_sbf_w  (coalesced write)
// ---------------------------------------------------------------------------
__global__ __launch_bounds__(256) void ta_all_k(
    const float* __restrict__ a_sbf, const float* __restrict__ a_sbf_w,
    float* __restrict__ taw)
{
    __shared__ __align__(16) float sA[256 * ADIM];
    __shared__ float sWa[ADIM * NBIL];
    const int tid = threadIdx.x;
    const size_t w0 = (size_t)blockIdx.x * 256;

    {
        const float4* src = (const float4*)(a_sbf + w0 * ADIM);
        float4* dst = (float4*)sA;
        for (int i = tid; i < (256 * ADIM) / 4; i += 256) dst[i] = src[i];
    }
    for (int i = tid; i < ADIM * NBIL; i += 256) sWa[i] = a_sbf_w[i];
    __syncthreads();

    float ta[NBIL];
    #pragma unroll
    for (int j = 0; j < NBIL; ++j) ta[j] = 0.0f;
    const float* row = sA + tid * ADIM;
    #pragma unroll
    for (int k = 0; k < ADIM; ++k) {
        float v = row[k];
        #pragma unroll
        for (int j = 0; j < NBIL; ++j) ta[j] = fmaf(v, sWa[k * NBIL + j], ta[j]);
    }
    float4* dst = (float4*)(taw + (w0 + tid) * NBIL);
    dst[0] = make_float4(ta[0], ta[1], ta[2], ta[3]);
    dst[1] = make_float4(ta[4], ta[5], ta[6], ta[7]);
}

// ---------------------------------------------------------------------------
// triplet stage B: grid = 128 edge-groups x 4 kj-slices. LDS bin per group,
// coalesced atomic writeback.
// ---------------------------------------------------------------------------
__global__ __launch_bounds__(1024) void seg_reduce_k(
    const float* __restrict__ taw, const int* __restrict__ kj_idx,
    float* __restrict__ ta_sum)
{
    __shared__ float acc[EB2 * NBIL];                  // 64 KB
    const int tid = threadIdx.x;
    const int eg = blockIdx.x >> 2;
    const int sl = blockIdx.x & 3;
    const int lo = eg * EB2;

    for (int i = tid; i < EB2 * NBIL; i += 1024) acc[i] = 0.f;
    __syncthreads();

    const int4* kj4 = (const int4*)kj_idx;
    const int i0 = sl * (N_TRI / 4 / NSL);
    const int i1 = i0 + (N_TRI / 4 / NSL);
    for (int i = i0 + tid; i < i1; i += 1024) {
        int4 v = kj4[i];
        int w0 = i * 4;
        #pragma unroll
        for (int k = 0; k < 4; ++k) {
            int e = (k == 0) ? v.x : (k == 1) ? v.y : (k == 2) ? v.z : v.w;
            unsigned d = (unsigned)(e - lo);
            if (d < (unsigned)EB2) {
                const float4* p = (const float4*)(taw + (size_t)(w0 + k) * NBIL);
                float4 a = p[0], b = p[1];
                float* q = acc + d * NBIL;
                atomicAdd(q + 0, a.x); atomicAdd(q + 1, a.y);
                atomicAdd(q + 2, a.z); atomicAdd(q + 3, a.w);
                atomicAdd(q + 4, b.x); atomicAdd(q + 5, b.y);
                atomicAdd(q + 6, b.z); atomicAdd(q + 7, b.w);
            }
        }
    }
    __syncthreads();
    for (int i = tid; i < EB2 * NBIL; i += 1024)
        unsafeAtomicAdd(ta_sum + (size_t)lo * NBIL + i, acc[i]);
}

// ---------------------------------------------------------------------------
// fallback triplet (scattered hw atomics) when ws too small
// ---------------------------------------------------------------------------
__global__ __launch_bounds__(256) void triplet_atomic_k(
    const float* __restrict__ a_sbf, const float* __restrict__ a_sbf_w,
    const int* __restrict__ kj_idx, float* __restrict__ ta_sum)
{
    __shared__ __align__(16) float sA[256 * ADIM];
    __shared__ float sWa[ADIM * NBIL];
    const int tid = threadIdx.x;
    const size_t w0 = (size_t)blockIdx.x * 256;
    {
        const float4* src = (const float4*)(a_sbf + w0 * ADIM);
        float4* dst = (float4*)sA;
        for (int i = tid; i < (256 * ADIM) / 4; i += 256) dst[i] = src[i];
    }
    for (int i = tid; i < ADIM * NBIL; i += 256) sWa[i] = a_sbf_w[i];
    __syncthreads();
    float ta[NBIL];
    #pragma unroll
    for (int j = 0; j < NBIL; ++j) ta[j] = 0.0f;
    const float* row = sA + tid * ADIM;
    #pragma unroll
    for (int k = 0; k < ADIM; ++k) {
        float v = row[k];
        #pragma unroll
        for (int j = 0; j < NBIL; ++j) ta[j] = fmaf(v, sWa[k * NBIL + j], ta[j]);
    }
    const int e = kj_idx[w0 + tid];
    float* dst = ta_sum + (size_t)e * NBIL;
    #pragma unroll
    for (int j = 0; j < NBIL; ++j) unsafeAtomicAdd(dst + j, ta[j]);
}

// ---------------------------------------------------------------------------
// fused edge kernel: TE=64, 4 waves (col-split). Round-5 structure +
// packed-dword LDS, fast silu, zac-seeded MFMA, bias/e_rbf_w from L2.
// ---------------------------------------------------------------------------
__global__ __launch_bounds__(NTHR) void edge_main_k(
    const float* __restrict__ m_ji, const float* __restrict__ e_rbf,
    const float* __restrict__ ta_sum, const unsigned short* __restrict__ wt,
    const float* __restrict__ nbr_m_b, const float* __restrict__ e_rbf_w,
    const float* __restrict__ m_ji_b, const float* __restrict__ post_b,
    const float* __restrict__ res_b, float* __restrict__ out)
{
    __shared__ __align__(16) unsigned int sXd[TE * SXD];   // 17.4 KB act
    __shared__ __align__(16) unsigned int sTd[TE * SXD];   // 17.4 KB transf
    __shared__ __align__(16) float sTAT[NBIL * TE];        // ta transposed
    __shared__ __align__(16) float sET[NRBF * TE];         // e_rbf transposed

    const int tid  = threadIdx.x;
    const int lane = tid & 63;
    const int ml   = lane & 15;
    const int g    = lane >> 4;
    const int wq   = tid >> 6;         // wave id 0..3
    const int n0   = wq * 32;
    const int q16  = wq * 16;
    const size_t e0 = (size_t)blockIdx.x * TE;

    bf16x8 A[4][2], Bf[2][4];
    f32x4 acc[4][2], xr[4][2], zac;
    float b0, b1;

    auto prefB = [&](const unsigned short* wtm, int ldk, int kbase) {
        #pragma unroll
        for (int nt = 0; nt < 2; ++nt) {
            const unsigned short* wb =
                wtm + (size_t)(n0 + nt * 16 + ml) * ldk + kbase + g * 8;
            #pragma unroll
            for (int ks = 0; ks < 4; ++ks)
                Bf[nt][ks] = *(const bf16x8*)(wb + ks * 32);
        }
    };
    auto ldbias = [&](const float* bp) {
        b0 = bp[n0 + ml]; b1 = bp[n0 + 16 + ml];
    };

    prefB(wt + 1 * 16384, DIM, 0);                     // m_ji_w for stage 1
    ldbias(m_ji_b);
    zac[0] = 0.f; zac[1] = 0.f; zac[2] = 0.f; zac[3] = 0.f;

    // ---- prologue staging: m_ji packed+permuted, ta/e transposed
    #pragma unroll
    for (int i = 0; i < 4; ++i) {
        int q = tid + i * NTHR;                        // 1024 chunks of 4 dw
        int row = q >> 4, sub = q & 15;
        int dq = sub >> 2, c4 = (sub & 3) * 4;
        const float* src = m_ji + (e0 + row) * DIM + dq * 32 + c4;
        float4 a = *(const float4*)(src);
        float4 b = *(const float4*)(src + 16);
        uint4 d;
        d.x = pk2(a.x, b.x); d.y = pk2(a.y, b.y);
        d.z = pk2(a.z, b.z); d.w = pk2(a.w, b.w);
        *(uint4*)(sXd + row * SXD + dq * 16 + c4) = d;
    }
    #pragma unroll
    for (int i = 0; i < 2; ++i) {
        int idx = tid + i * NTHR;                      // 512: j-major
        int j = idx >> 6, e = idx & 63;
        sTAT[j * TE + e] = ta_sum[(e0 + e) * NBIL + j];
    }
    for (int i = tid; i < NRBF * TE; i += NTHR) {
        int j = i >> 6, e = i & 63;
        sET[j * TE + e] = e_rbf[(e0 + e) * NRBF + j];
    }
    __syncthreads();

    auto loadA = [&](int h) {
        const unsigned short* base = (const unsigned short*)sXd;
        #pragma unroll
        for (int mt = 0; mt < 4; ++mt) {
            const unsigned short* rb = base + (mt * 16 + ml) * (SXD * 2) + h * 64 + g * 8;
            A[mt][0] = *(const bf16x8*)(rb);
            A[mt][1] = *(const bf16x8*)(rb + 32);
        }
    };
    auto mfmaH = [&](int h, bool seed) {
        #pragma unroll
        for (int kk = 0; kk < 2; ++kk)
        #pragma unroll
        for (int nt = 0; nt < 2; ++nt)
        #pragma unroll
        for (int mt = 0; mt < 4; ++mt)
            acc[mt][nt] = __builtin_amdgcn_mfma_f32_16x16x32_bf16(
                A[mt][kk], Bf[nt][h * 2 + kk],
                (seed && kk == 0) ? zac : acc[mt][nt], 0, 0, 0);
    };
    auto gemm_full = [&]() { loadA(0); mfmaH(0, true); loadA(1); mfmaH(1, false); };
    auto store_sX = [&](f32x4 (&v)[4][2]) {            // packed dwords, guarded
        __syncthreads();
        #pragma unroll
        for (int mt = 0; mt < 4; ++mt)
        #pragma unroll
        for (int r = 0; r < 4; ++r)
            sXd[(mt * 16 + g * 4 + r) * SXD + q16 + ml] = pk2(v[mt][0][r], v[mt][1][r]);
        __syncthreads();
    };

    // ---- S1: transf = silu(m_ji @ m_ji_w + b) -> sTd (lane-local, no barrier)
    gemm_full();
    prefB(wt + 0 * 16384, DIM, 0);                     // nbr_m_w next
    #pragma unroll
    for (int mt = 0; mt < 4; ++mt)
    #pragma unroll
    for (int r = 0; r < 4; ++r)
        sTd[(mt * 16 + g * 4 + r) * SXD + q16 + ml] =
            pk2(silu_f(acc[mt][0][r] + b0), silu_f(acc[mt][1][r] + b1));

    // ---- S2: me = silu(m_ji @ nbr_m_w + b) * (e_rbf @ e_rbf_w)  (A = m_ji)
    ldbias(nbr_m_b);
    float ewc[2][NRBF];
    #pragma unroll
    for (int nt = 0; nt < 2; ++nt)
    #pragma unroll
    for (int q = 0; q < NRBF; ++q)
        ewc[nt][q] = e_rbf_w[q * DIM + n0 + nt * 16 + ml];
    gemm_full();
    const unsigned short* fwb = wt + 9 * 16384;
    prefB(fwb, NBIL * DIM, 0);                         // bilinear j=0
    #pragma unroll
    for (int mt = 0; mt < 4; ++mt) {
        f32x4 er[NRBF];
        #pragma unroll
        for (int q = 0; q < NRBF; ++q)
            er[q] = *(const f32x4*)(sET + q * TE + mt * 16 + g * 4);
        #pragma unroll
        for (int r = 0; r < 4; ++r) {
            float te0 = 0.f, te1 = 0.f;
            #pragma unroll
            for (int q = 0; q < NRBF; ++q) {
                te0 = fmaf(er[q][r], ewc[0][q], te0);
                te1 = fmaf(er[q][r], ewc[1][q], te1);
            }
            acc[mt][0][r] = silu_f(acc[mt][0][r] + b0) * te0;
            acc[mt][1][r] = silu_f(acc[mt][1][r] + b1) * te1;
        }
    }
    store_sX(acc);                                     // sXd = me

    // ---- S3 bilinear: xr = transf + sum_j ta_j * (me @ fw_j^T)
    #pragma unroll
    for (int mt = 0; mt < 4; ++mt)
    #pragma unroll
    for (int r = 0; r < 4; ++r) {
        unsigned int t = sTd[(mt * 16 + g * 4 + r) * SXD + q16 + ml];
        xr[mt][0][r] = bf2f((unsigned short)(t & 0xffff));
        xr[mt][1][r] = bf2f((unsigned short)(t >> 16));
    }
    for (int j = 0; j < NBIL; ++j) {
        gemm_full();                                   // zac-seeded
        if (j < NBIL - 1) prefB(fwb, NBIL * DIM, (j + 1) * DIM);
        else              prefB(wt + 3 * 16384, DIM, 0);
        #pragma unroll
        for (int mt = 0; mt < 4; ++mt) {
            f32x4 tv = *(const f32x4*)(sTAT + j * TE + mt * 16 + g * 4);
            #pragma unroll
            for (int nt = 0; nt < 2; ++nt)
            #pragma unroll
            for (int r = 0; r < 4; ++r)
                xr[mt][nt][r] = fmaf(tv[r], acc[mt][nt][r], xr[mt][nt][r]);
        }
    }
    store_sX(xr);                                      // sXd = x

    // ---- res0
    ldbias(res_b + 0);
    gemm_full(); prefB(wt + 4 * 16384, DIM, 0);
    #pragma unroll
    for (int mt = 0; mt < 4; ++mt)
    #pragma unroll
    for (int r = 0; r < 4; ++r) {
        acc[mt][0][r] = silu_f(acc[mt][0][r] + b0);
        acc[mt][1][r] = silu_f(acc[mt][1][r] + b1);
    }
    store_sX(acc);
    ldbias(res_b + 128);
    gemm_full(); prefB(wt + 2 * 16384, DIM, 0);
    #pragma unroll
    for (int mt = 0; mt < 4; ++mt)
    #pragma unroll
    for (int r = 0; r < 4; ++r) {
        xr[mt][0][r] += silu_f(acc[mt][0][r] + b0);
        xr[mt][1][r] += silu_f(acc[mt][1][r] + b1);
    }
    store_sX(xr);

    // ---- post: x = silu(x @ post_w + b) + transf
    ldbias(post_b);
    gemm_full(); prefB(wt + 5 * 16384, DIM, 0);
    #pragma unroll
    for (int mt = 0; mt < 4; ++mt)
    #pragma unroll
    for (int r = 0; r < 4; ++r) {
        unsigned int t = sTd[(mt * 16 + g * 4 + r) * SXD + q16 + ml];
        xr[mt][0][r] = silu_f(acc[mt][0][r] + b0) + bf2f((unsigned short)(t & 0xffff));
        xr[mt][1][r] = silu_f(acc[mt][1][r] + b1) + bf2f((unsigned short)(t >> 16));
    }
    store_sX(xr);

    // ---- res1
    ldbias(res_b + 256);
    gemm_full(); prefB(wt + 6 * 16384, DIM, 0);
    #pragma unroll
    for (int mt = 0; mt < 4; ++mt)
    #pragma unroll
    for (int r = 0; r < 4; ++r) {
        acc[mt][0][r] = silu_f(acc[mt][0][r] + b0);
        acc[mt][1][r] = silu_f(acc[mt][1][r] + b1);
    }
    store_sX(acc);
    ldbias(res_b + 384);
    gemm_full(); prefB(wt + 7 * 16384, DIM, 0);
    #pragma unroll
    for (int mt = 0; mt < 4; ++mt)
    #pragma unroll
    for (int r = 0; r < 4; ++r) {
        xr[mt][0][r] += silu_f(acc[mt][0][r] + b0);
        xr[mt][1][r] += silu_f(acc[mt][1][r] + b1);
    }
    store_sX(xr);

    // ---- res2 + fused store
    ldbias(res_b + 512);
    gemm_full(); prefB(wt + 8 * 16384, DIM, 0);
    #pragma unroll
    for (int mt = 0; mt < 4; ++mt)
    #pragma unroll
    for (int r = 0; r < 4; ++r) {
        acc[mt][0][r] = silu_f(acc[mt][0][r] + b0);
        acc[mt][1][r] = silu_f(acc[mt][1][r] + b1);
    }
    store_sX(acc);
    ldbias(res_b + 640);
    gemm_full();
    #pragma unroll
    for (int mt = 0; mt < 4; ++mt)
    #pragma unroll
    for (int r = 0; r < 4; ++r) {
        int row = mt * 16 + g * 4 + r;
        out[(e0 + row) * DIM + n0 + ml]      = silu_f(acc[mt][0][r] + b0) + xr[mt][0][r];
        out[(e0 + row) * DIM + n0 + 16 + ml] = silu_f(acc[mt][1][r] + b1) + xr[mt][1][r];
    }
}

// ---------------------------------------------------------------------------
extern "C" void kernel_launch(void* const* d_in, const int* in_sizes, int n_in,
                              void* d_out, int out_size, void* d_ws, size_t ws_size,
                              hipStream_t stream)
{
    (void)in_sizes; (void)n_in; (void)out_size;
    const float* m_ji    = (const float*)d_in[0];
    const float* e_rbf   = (const float*)d_in[1];
    const float* a_sbf   = (const float*)d_in[2];
    const int*   kj_idx  = (const int*)d_in[5];
    const float* nbr_m_w = (const float*)d_in[6];
    const float* nbr_m_b = (const float*)d_in[7];
    const float* e_rbf_w = (const float*)d_in[8];
    const float* a_sbf_w = (const float*)d_in[9];
    const float* final_w = (const float*)d_in[10];
    const float* m_ji_w  = (const float*)d_in[11];
    const float* m_ji_b  = (const float*)d_in[12];
    const float* post_w  = (const float*)d_in[13];
    const float* post_b  = (const float*)d_in[14];
    const float* res_w   = (const float*)d_in[15];
    const float* res_b   = (const float*)d_in[16];
    float* out = (float*)d_out;

    const size_t taB  = (size_t)N_EDGE * NBIL * sizeof(float);      // 8.4 MB
    const size_t wtB  = (size_t)278528 * sizeof(unsigned short);    // 0.56 MB
    const size_t tawB = (size_t)N_TRI * NBIL * sizeof(float);       // 33.6 MB

    float* ta_sum = (float*)d_ws;
    unsigned short* wt = (unsigned short*)((char*)d_ws + taB);
    float* taw = (float*)((char*)d_ws + taB + wtB);

    prep_w_k<<<1088, 256, 0, stream>>>(nbr_m_w, m_ji_w, post_w, res_w, final_w, wt);
    hipMemsetAsync(ta_sum, 0, taB, stream);

    if (ws_size >= taB + wtB + tawB) {
        ta_all_k<<<N_TRI / 256, 256, 0, stream>>>(a_sbf, a_sbf_w, taw);
        seg_reduce_k<<<(N_EDGE / EB2) * NSL, 1024, 0, stream>>>(taw, kj_idx, ta_sum);
    } else {
        triplet_atomic_k<<<N_TRI / 256, 256, 0, stream>>>(a_sbf, a_sbf_w, kj_idx, ta_sum);
    }
    edge_main_k<<<N_EDGE / TE, NTHR, 0, stream>>>(m_ji, e_rbf, ta_sum, wt,
        nbr_m_b, e_rbf_w, m_ji_b, post_b, res_b, out);
}